// Round 2
// 1199.783 us; speedup vs baseline: 1.0933x; 1.0933x over previous
//
#include <hip/hip_runtime.h>
#include <hip/hip_bf16.h>

// Problem constants (match reference)
#define MM 12288
#define NCH 8      // B * C_IN
#define COUT 16
#define KK 5
#define ROWS 4     // output rows per wave
#define WPB 8      // waves per block
#define RB (ROWS * WPB)   // 32 rows per block
#define CHUNK 256  // columns per staged chunk

// Block = 512 threads (8 waves). Each iteration the block stages the vin chunk
// [NCH][CHUNK] (8 KB) into LDS ONCE (wave w stages channel w, one float4 per
// thread, fully coalesced), then all 8 waves consume it from LDS. This cuts
// global vin traffic 8x vs the per-wave kernel (1.18 GB -> 147 MB per pass),
// leaving L streaming (604 MB/pass) as essentially the only HBM traffic.
// L loads are issued at the top of the iteration so they are in flight across
// the two staging barriers (the barrier vmcnt drain then completes them just
// before the FMA block needs them).
__global__ __launch_bounds__(512) void matpanel_kernel(
        const float* __restrict__ L,
        const float* __restrict__ vin,   // [NCH][MM]
        float* __restrict__ vout) {      // [NCH][MM]
    const int tid  = threadIdx.x;
    const int lane = tid & 63;           // 0..63 within wave
    const int wave = tid >> 6;           // 0..7
    const int row0 = blockIdx.x * RB + wave * ROWS;

    // Staging assignment: wave index == channel index (8 waves, 8 channels),
    // lane*4 covers the 256 columns of the chunk. 512 threads x float4 = 2048
    // floats = the whole [8][256] chunk.
    const int sc = wave;
    const int sj = lane * 4;

    __shared__ float sv[NCH][CHUNK];     // 8 KB

    float acc[ROWS][NCH];
#pragma unroll
    for (int r = 0; r < ROWS; ++r)
#pragma unroll
        for (int c = 0; c < NCH; ++c) acc[r][c] = 0.f;

    for (int it = 0; it < MM / CHUNK; ++it) {
        const int jbase = it * CHUNK;

        // Issue all global loads for this iteration up front (5 x float4):
        // they stay in flight while we wait at the barriers.
        const float4 t = *(const float4*)(vin + (size_t)sc * MM + jbase + sj);
        float4 la[ROWS];
#pragma unroll
        for (int r = 0; r < ROWS; ++r)
            la[r] = *(const float4*)(L + (size_t)(row0 + r) * MM + jbase + lane * 4);

        __syncthreads();                 // all waves done READING sv from prev iter
        *(float4*)(&sv[sc][sj]) = t;
        __syncthreads();                 // staged chunk visible to all waves

        // Consume: conflict-free stride-16B ds_read_b128 per channel,
        // reused across 4 rows held in registers.
#pragma unroll
        for (int c = 0; c < NCH; ++c) {
            const float4 v = *(const float4*)(&sv[c][lane * 4]);
#pragma unroll
            for (int r = 0; r < ROWS; ++r) {
                acc[r][c] += la[r].x * v.x + la[r].y * v.y
                           + la[r].z * v.z + la[r].w * v.w;
            }
        }
    }

    // Cross-lane reduction: 32 values (r*8+c) distributed one-per-lane.
    // (Verbatim from the verified previous kernel; per-wave, width 64.)
    float val[ROWS * NCH];
#pragma unroll
    for (int r = 0; r < ROWS; ++r)
#pragma unroll
        for (int c = 0; c < NCH; ++c) val[r * NCH + c] = acc[r][c];

    // Fold upper 32 lanes onto lower 32 (both halves end with pair sums).
#pragma unroll
    for (int v = 0; v < 32; ++v) val[v] += __shfl_xor(val[v], 32, 64);

    // Butterfly: value-index bit d <-> lane bit d.
#pragma unroll
    for (int d = 16; d >= 1; d >>= 1) {
        const bool up = (lane & d) != 0;
#pragma unroll
        for (int v = 0; v < 16; ++v) {
            if (v < d) {
                const float keep = up ? val[v + d] : val[v];
                const float send = up ? val[v] : val[v + d];
                const float recv = __shfl_xor(send, d, 64);
                val[v] = keep + recv;
            }
        }
    }

    // Lane l (l < 32) holds the full sum for value index l: r = l>>3, c = l&7.
    if (lane < 32) {
        const int r = lane >> 3;
        const int c = lane & 7;
        vout[(size_t)c * MM + row0 + r] = val[0];
    }
}

// y[o][m] = bias[o] + sum_{c,k} theta[o][c][k] * P_k[c][m],  P_0 = x
__global__ __launch_bounds__(256) void combine_kernel(
        const float* __restrict__ x,      // [NCH][MM]  (power 0)
        const float* __restrict__ P,      // [KK-1][NCH][MM] (powers 1..4)
        const float* __restrict__ theta,  // [COUT][NCH][KK]
        const float* __restrict__ bias,   // [COUT]
        float* __restrict__ y) {          // [COUT][MM]
    const int m = blockIdx.x * blockDim.x + threadIdx.x;
    if (m >= MM) return;

    float p[KK][NCH];
#pragma unroll
    for (int c = 0; c < NCH; ++c) p[0][c] = x[(size_t)c * MM + m];
#pragma unroll
    for (int k = 1; k < KK; ++k)
#pragma unroll
        for (int c = 0; c < NCH; ++c)
            p[k][c] = P[((size_t)(k - 1) * NCH + c) * MM + m];

#pragma unroll
    for (int o = 0; o < COUT; ++o) {
        float acc = bias[o];
#pragma unroll
        for (int c = 0; c < NCH; ++c)
#pragma unroll
            for (int k = 0; k < KK; ++k)
                acc += theta[(o * NCH + c) * KK + k] * p[k][c];
        y[(size_t)o * MM + m] = acc;
    }
}

extern "C" void kernel_launch(void* const* d_in, const int* in_sizes, int n_in,
                              void* d_out, int out_size, void* d_ws, size_t ws_size,
                              hipStream_t stream) {
    const float* L     = (const float*)d_in[0];  // [MM][MM]
    const float* x     = (const float*)d_in[1];  // [1][NCH][MM]
    const float* theta = (const float*)d_in[2];  // [COUT][NCH][KK]
    const float* bias  = (const float*)d_in[3];  // [1][COUT][1]
    float* out = (float*)d_out;                  // [1][COUT][MM]
    float* P   = (float*)d_ws;                   // 4 * NCH * MM floats = 1.57 MB

    const size_t S = (size_t)NCH * MM;
    const int grid = MM / RB;  // 384 blocks of 512 threads

    matpanel_kernel<<<grid, 512, 0, stream>>>(L, x,         P);
    matpanel_kernel<<<grid, 512, 0, stream>>>(L, P,         P + S);
    matpanel_kernel<<<grid, 512, 0, stream>>>(L, P + S,     P + 2 * S);
    matpanel_kernel<<<grid, 512, 0, stream>>>(L, P + 2 * S, P + 3 * S);

    combine_kernel<<<(MM + 255) / 256, 256, 0, stream>>>(x, P, theta, bias, out);
}

// Round 3
// 1159.128 us; speedup vs baseline: 1.1316x; 1.0351x over previous
//
#include <hip/hip_runtime.h>
#include <hip/hip_bf16.h>

// Problem constants (match reference)
#define MM 12288
#define NCH 8      // B * C_IN
#define COUT 16
#define KK 5
#define ROWS 4     // output rows per wave
#define WPB 4      // waves per block
#define RB (ROWS * WPB)    // 16 rows per block
#define CHUNK 256  // columns per staged chunk
#define NIT (MM / CHUNK)   // 48 iterations

// Block = 256 threads (4 waves), grid = 768 = exactly 3 blocks/CU (balanced).
// Software-pipelined: LDS vin chunk is double-buffered; each iteration issues
// the NEXT chunk's L + vin loads right after the single barrier, BEFORE the
// compute phase, so the loads are in flight during compute and the compiler's
// vmcnt(0) drain at the next barrier finds them already landed. One barrier
// per iteration (write buf[p], sync, compute buf[p]; next iter writes buf[p^1]
// which was last read before the previous barrier => safe).
__global__ __launch_bounds__(256) void matpanel_kernel(
        const float* __restrict__ L,
        const float* __restrict__ vin,   // [NCH][MM]
        float* __restrict__ vout) {      // [NCH][MM]
    const int tid  = threadIdx.x;
    const int lane = tid & 63;           // 0..63 within wave
    const int wave = tid >> 6;           // 0..3
    const int row0 = blockIdx.x * RB + wave * ROWS;

    // Staging: 256 threads x 2 float4 = 2048 floats = the whole [8][256] chunk.
    // First float4 covers channels 0..3, second covers channels 4..7.
    const int sch  = tid >> 6;           // 0..3
    const int scol = (tid & 63) * 4;     // 0..252

    __shared__ float sv[2][NCH][CHUNK];  // 2 x 8 KB

    float acc[ROWS][NCH];
#pragma unroll
    for (int r = 0; r < ROWS; ++r)
#pragma unroll
        for (int c = 0; c < NCH; ++c) acc[r][c] = 0.f;

    // Prologue: issue chunk 0 loads.
    float4 t0 = *(const float4*)(vin + (size_t)sch * MM + scol);
    float4 t1 = *(const float4*)(vin + (size_t)(sch + 4) * MM + scol);
    float4 la[ROWS];
#pragma unroll
    for (int r = 0; r < ROWS; ++r)
        la[r] = *(const float4*)(L + (size_t)(row0 + r) * MM + lane * 4);

    int p = 0;
#pragma unroll 2
    for (int it = 0; it < NIT; ++it) {
        // Write the staged chunk (waitcnt for t0/t1 lands here).
        *(float4*)(&sv[p][sch][scol])     = t0;
        *(float4*)(&sv[p][sch + 4][scol]) = t1;
        __syncthreads();

        // Prefetch next chunk (clamped on the last iteration: harmless
        // re-read keeps the loop body branch-free and uniform).
        const int itn   = (it + 1 < NIT) ? (it + 1) : it;
        const int jnext = itn * CHUNK;
        float4 t0n = *(const float4*)(vin + (size_t)sch * MM + jnext + scol);
        float4 t1n = *(const float4*)(vin + (size_t)(sch + 4) * MM + jnext + scol);
        float4 lan[ROWS];
#pragma unroll
        for (int r = 0; r < ROWS; ++r)
            lan[r] = *(const float4*)(L + (size_t)(row0 + r) * MM + jnext + lane * 4);

        // Compute on the staged chunk: conflict-free stride-16B ds_read_b128,
        // each channel value reused across 4 rows held in registers.
#pragma unroll
        for (int c = 0; c < NCH; ++c) {
            const float4 v = *(const float4*)(&sv[p][c][lane * 4]);
#pragma unroll
            for (int r = 0; r < ROWS; ++r) {
                acc[r][c] += la[r].x * v.x + la[r].y * v.y
                           + la[r].z * v.z + la[r].w * v.w;
            }
        }

        // Rotate prefetched registers (unroll-2 lets the compiler rename
        // instead of copying).
#pragma unroll
        for (int r = 0; r < ROWS; ++r) la[r] = lan[r];
        t0 = t0n;
        t1 = t1n;
        p ^= 1;
    }

    // Cross-lane reduction: 32 values (r*8+c) distributed one-per-lane.
    // (Verbatim from the verified kernel; per-wave, width 64.)
    float val[ROWS * NCH];
#pragma unroll
    for (int r = 0; r < ROWS; ++r)
#pragma unroll
        for (int c = 0; c < NCH; ++c) val[r * NCH + c] = acc[r][c];

    // Fold upper 32 lanes onto lower 32 (both halves end with pair sums).
#pragma unroll
    for (int v = 0; v < 32; ++v) val[v] += __shfl_xor(val[v], 32, 64);

    // Butterfly: value-index bit d <-> lane bit d.
#pragma unroll
    for (int d = 16; d >= 1; d >>= 1) {
        const bool up = (lane & d) != 0;
#pragma unroll
        for (int v = 0; v < 16; ++v) {
            if (v < d) {
                const float keep = up ? val[v + d] : val[v];
                const float send = up ? val[v] : val[v + d];
                const float recv = __shfl_xor(send, d, 64);
                val[v] = keep + recv;
            }
        }
    }

    // Lane l (l < 32) holds the full sum for value index l: r = l>>3, c = l&7.
    if (lane < 32) {
        const int r = lane >> 3;
        const int c = lane & 7;
        vout[(size_t)c * MM + row0 + r] = val[0];
    }
}

// y[o][m] = bias[o] + sum_{c,k} theta[o][c][k] * P_k[c][m],  P_0 = x
__global__ __launch_bounds__(256) void combine_kernel(
        const float* __restrict__ x,      // [NCH][MM]  (power 0)
        const float* __restrict__ P,      // [KK-1][NCH][MM] (powers 1..4)
        const float* __restrict__ theta,  // [COUT][NCH][KK]
        const float* __restrict__ bias,   // [COUT]
        float* __restrict__ y) {          // [COUT][MM]
    const int m = blockIdx.x * blockDim.x + threadIdx.x;
    if (m >= MM) return;

    float p[KK][NCH];
#pragma unroll
    for (int c = 0; c < NCH; ++c) p[0][c] = x[(size_t)c * MM + m];
#pragma unroll
    for (int k = 1; k < KK; ++k)
#pragma unroll
        for (int c = 0; c < NCH; ++c)
            p[k][c] = P[((size_t)(k - 1) * NCH + c) * MM + m];

#pragma unroll
    for (int o = 0; o < COUT; ++o) {
        float acc = bias[o];
#pragma unroll
        for (int c = 0; c < NCH; ++c)
#pragma unroll
            for (int k = 0; k < KK; ++k)
                acc += theta[(o * NCH + c) * KK + k] * p[k][c];
        y[(size_t)o * MM + m] = acc;
    }
}

extern "C" void kernel_launch(void* const* d_in, const int* in_sizes, int n_in,
                              void* d_out, int out_size, void* d_ws, size_t ws_size,
                              hipStream_t stream) {
    const float* L     = (const float*)d_in[0];  // [MM][MM]
    const float* x     = (const float*)d_in[1];  // [1][NCH][MM]
    const float* theta = (const float*)d_in[2];  // [COUT][NCH][KK]
    const float* bias  = (const float*)d_in[3];  // [1][COUT][1]
    float* out = (float*)d_out;                  // [1][COUT][MM]
    float* P   = (float*)d_ws;                   // 4 * NCH * MM floats = 1.57 MB

    const size_t S = (size_t)NCH * MM;
    const int grid = MM / RB;  // 768 blocks of 256 threads = 3 blocks/CU exactly

    matpanel_kernel<<<grid, 256, 0, stream>>>(L, x,         P);
    matpanel_kernel<<<grid, 256, 0, stream>>>(L, P,         P + S);
    matpanel_kernel<<<grid, 256, 0, stream>>>(L, P + S,     P + 2 * S);
    matpanel_kernel<<<grid, 256, 0, stream>>>(L, P + 2 * S, P + 3 * S);

    combine_kernel<<<(MM + 255) / 256, 256, 0, stream>>>(x, P, theta, bias, out);
}